// Round 1
// baseline (2047.074 us; speedup 1.0000x reference)
//
#include <hip/hip_runtime.h>

#define NN 10000
#define NE 160000
#define RS 65  // LDS row stride (64 edges + 1 pad)

__device__ __forceinline__ float silu_f(float x) {
    return x / (1.0f + __expf(-x));
}

// ---------------- Kernel 1: node transform ----------------
// scalars = x0 @ W_scalar * inv ; h0 = x0 @ W_up0 * inv ; h1[n][o][i] = sum_m x1[n][m][i] W_up1[m][o] * inv
__global__ __launch_bounds__(256) void node_transform(
    const float* __restrict__ node_feats,
    const float* __restrict__ W_scalar,
    const float* __restrict__ W_up0,
    const float* __restrict__ W_up1,
    float* __restrict__ scalars,
    float* __restrict__ h0,
    float* __restrict__ h1)
{
    __shared__ float xs[8 * 512];
    const int t = threadIdx.x;
    const int bn = blockIdx.x * 8;

    const float4* src = (const float4*)(node_feats + (size_t)bn * 512);
    float4* dst = (float4*)xs;
    #pragma unroll
    for (int i = 0; i < 4; ++i) dst[t + 256 * i] = src[t + 256 * i];
    __syncthreads();

    const int tn = t >> 5;      // 0..7 node in tile
    const int to = t & 31;      // 0..31
    const int n = bn + tn;

    float sc[4] = {0.f,0.f,0.f,0.f};
    float a0[4] = {0.f,0.f,0.f,0.f};
    float a1[4][3] = {};

    const float* x0 = xs + tn * 512;
    const float* x1 = xs + tn * 512 + 128;

    for (int k = 0; k < 128; ++k) {
        float xv = x0[k];
        float xa = x1[k*3+0], xb = x1[k*3+1], xc = x1[k*3+2];
        #pragma unroll
        for (int q = 0; q < 4; ++q) {
            int o = to + 32 * q;
            float wsc = W_scalar[k*128 + o];
            float w0  = W_up0[k*128 + o];
            float w1  = W_up1[k*128 + o];
            sc[q] = fmaf(xv, wsc, sc[q]);
            a0[q] = fmaf(xv, w0,  a0[q]);
            a1[q][0] = fmaf(xa, w1, a1[q][0]);
            a1[q][1] = fmaf(xb, w1, a1[q][1]);
            a1[q][2] = fmaf(xc, w1, a1[q][2]);
        }
    }
    const float inv = 0.08838834764831845f; // 1/sqrt(128)
    #pragma unroll
    for (int q = 0; q < 4; ++q) {
        int o = to + 32 * q;
        scalars[n*128 + o] = sc[q] * inv;
        h0[n*128 + o]      = a0[q] * inv;
        h1[(n*128 + o)*3 + 0] = a1[q][0] * inv;
        h1[(n*128 + o)*3 + 1] = a1[q][1] * inv;
        h1[(n*128 + o)*3 + 2] = a1[q][2] * inv;
    }
}

// ---------------- Kernel 2: edge MLP + tensor product + atomic scatter ----------------
__global__ __launch_bounds__(256) void edge_kernel(
    const float* __restrict__ scalars,
    const float* __restrict__ h0g,
    const float* __restrict__ h1g,
    const float* __restrict__ edge_attrs,
    const float* __restrict__ edge_feats,
    const float* __restrict__ lengths,
    const int* __restrict__ edge_index,
    const float* __restrict__ W1, const float* __restrict__ b1,
    const float* __restrict__ W2, const float* __restrict__ b2,
    const float* __restrict__ W3,
    float* __restrict__ agg0, float* __restrict__ agg1)
{
    __shared__ float in_s[265 * RS];
    __shared__ float h_s[128 * RS];
    __shared__ float h2_s[128 * RS];
    __shared__ int   s_s[64];
    __shared__ int   r_s[64];
    __shared__ float y_s[64 * 4];

    const int t = threadIdx.x;
    const int e0 = blockIdx.x * 64;

    if (t < 64) {
        int e = e0 + t;
        s_s[t] = edge_index[e];
        r_s[t] = edge_index[NE + e];
        float4 ea = *(const float4*)(edge_attrs + (size_t)e * 4);
        y_s[t*4+0] = ea.x; y_s[t*4+1] = ea.y; y_s[t*4+2] = ea.z; y_s[t*4+3] = ea.w;
        in_s[264 * RS + t] = lengths[e];
    }
    __syncthreads();

    for (int i = t; i < 64 * 8; i += 256) {
        int e = i >> 3, k = i & 7;
        in_s[(256 + k) * RS + e] = edge_feats[(size_t)(e0 + e) * 8 + k];
    }
    {
        const int e4 = t >> 2, j4 = t & 3;
        const float4* srow = (const float4*)(scalars + (size_t)s_s[e4] * 128);
        const float4* rrow = (const float4*)(scalars + (size_t)r_s[e4] * 128);
        #pragma unroll
        for (int m = 0; m < 8; ++m) {
            int k4 = j4 + 4 * m;
            float4 v = srow[k4];
            int k = k4 * 4;
            in_s[(k+0)*RS + e4] = v.x; in_s[(k+1)*RS + e4] = v.y;
            in_s[(k+2)*RS + e4] = v.z; in_s[(k+3)*RS + e4] = v.w;
            float4 u = rrow[k4];
            in_s[(128+k+0)*RS + e4] = u.x; in_s[(128+k+1)*RS + e4] = u.y;
            in_s[(128+k+2)*RS + e4] = u.z; in_s[(128+k+3)*RS + e4] = u.w;
        }
    }
    __syncthreads();

    const int te = t >> 5;      // 0..7
    const int to = t & 31;      // 0..31
    const int eb = te * 8;      // base edge in tile

    // ---- layer 1: (64,265)@(265,128) + b1, silu ----
    {
        float acc[8][4];
        #pragma unroll
        for (int i = 0; i < 8; ++i)
            #pragma unroll
            for (int q = 0; q < 4; ++q) acc[i][q] = 0.f;
        for (int k = 0; k < 265; ++k) {
            float w[4];
            #pragma unroll
            for (int q = 0; q < 4; ++q) w[q] = W1[k*128 + to + 32*q];
            #pragma unroll
            for (int i = 0; i < 8; ++i) {
                float v = in_s[k * RS + eb + i];
                #pragma unroll
                for (int q = 0; q < 4; ++q) acc[i][q] = fmaf(v, w[q], acc[i][q]);
            }
        }
        #pragma unroll
        for (int q = 0; q < 4; ++q) {
            float bb = b1[to + 32*q];
            #pragma unroll
            for (int i = 0; i < 8; ++i)
                h_s[(to + 32*q) * RS + eb + i] = silu_f(acc[i][q] + bb);
        }
    }
    __syncthreads();

    // ---- layer 2: (64,128)@(128,128) + b2, silu ----
    {
        float acc[8][4];
        #pragma unroll
        for (int i = 0; i < 8; ++i)
            #pragma unroll
            for (int q = 0; q < 4; ++q) acc[i][q] = 0.f;
        for (int k = 0; k < 128; ++k) {
            float w[4];
            #pragma unroll
            for (int q = 0; q < 4; ++q) w[q] = W2[k*128 + to + 32*q];
            #pragma unroll
            for (int i = 0; i < 8; ++i) {
                float v = h_s[k * RS + eb + i];
                #pragma unroll
                for (int q = 0; q < 4; ++q) acc[i][q] = fmaf(v, w[q], acc[i][q]);
            }
        }
        #pragma unroll
        for (int q = 0; q < 4; ++q) {
            float bb = b2[to + 32*q];
            #pragma unroll
            for (int i = 0; i < 8; ++i)
                h2_s[(to + 32*q) * RS + eb + i] = silu_f(acc[i][q] + bb);
        }
    }
    __syncthreads();

    // ---- layer 3 pass 1: chunks A (base 0) and B (base 256) ----
    {
        float accA[8][4], accB[8][4];
        #pragma unroll
        for (int i = 0; i < 8; ++i)
            #pragma unroll
            for (int q = 0; q < 4; ++q) { accA[i][q] = 0.f; accB[i][q] = 0.f; }
        for (int k = 0; k < 128; ++k) {
            float wa[4], wb[4];
            #pragma unroll
            for (int q = 0; q < 4; ++q) {
                wa[q] = W3[k*512 + to + 32*q];
                wb[q] = W3[k*512 + 256 + to + 32*q];
            }
            #pragma unroll
            for (int i = 0; i < 8; ++i) {
                float v = h2_s[k * RS + eb + i];
                #pragma unroll
                for (int q = 0; q < 4; ++q) {
                    accA[i][q] = fmaf(v, wa[q], accA[i][q]);
                    accB[i][q] = fmaf(v, wb[q], accB[i][q]);
                }
            }
        }
        #pragma unroll
        for (int i = 0; i < 8; ++i) {
            int e = eb + i;
            int sn = s_s[e], rn = r_s[e];
            float y0  = y_s[e*4+0];
            float y1x = y_s[e*4+1], y1y = y_s[e*4+2], y1z = y_s[e*4+3];
            #pragma unroll
            for (int q = 0; q < 4; ++q) {
                int o = to + 32*q;
                float xs0 = h0g[sn*128 + o];
                atomicAdd(agg0 + rn*256 + o, xs0 * y0 * accA[i][q]);
                float xb = xs0 * accB[i][q];
                atomicAdd(agg1 + (rn*256 + o)*3 + 0, xb * y1x);
                atomicAdd(agg1 + (rn*256 + o)*3 + 1, xb * y1y);
                atomicAdd(agg1 + (rn*256 + o)*3 + 2, xb * y1z);
            }
        }
    }

    // ---- layer 3 pass 2: chunks D (base 128) and C (base 384) ----
    {
        float accD[8][4], accC[8][4];
        #pragma unroll
        for (int i = 0; i < 8; ++i)
            #pragma unroll
            for (int q = 0; q < 4; ++q) { accD[i][q] = 0.f; accC[i][q] = 0.f; }
        for (int k = 0; k < 128; ++k) {
            float wd[4], wc[4];
            #pragma unroll
            for (int q = 0; q < 4; ++q) {
                wd[q] = W3[k*512 + 128 + to + 32*q];
                wc[q] = W3[k*512 + 384 + to + 32*q];
            }
            #pragma unroll
            for (int i = 0; i < 8; ++i) {
                float v = h2_s[k * RS + eb + i];
                #pragma unroll
                for (int q = 0; q < 4; ++q) {
                    accD[i][q] = fmaf(v, wd[q], accD[i][q]);
                    accC[i][q] = fmaf(v, wc[q], accC[i][q]);
                }
            }
        }
        const float rs3 = 0.57735026918962576f; // 1/sqrt(3)
        #pragma unroll
        for (int i = 0; i < 8; ++i) {
            int e = eb + i;
            int sn = s_s[e], rn = r_s[e];
            float y0  = y_s[e*4+0];
            float y1x = y_s[e*4+1], y1y = y_s[e*4+2], y1z = y_s[e*4+3];
            #pragma unroll
            for (int q = 0; q < 4; ++q) {
                int o = to + 32*q;
                float x1x = h1g[(sn*128 + o)*3 + 0];
                float x1y = h1g[(sn*128 + o)*3 + 1];
                float x1z = h1g[(sn*128 + o)*3 + 2];
                float dd = (x1x*y1x + x1y*y1y + x1z*y1z) * rs3;
                atomicAdd(agg0 + rn*256 + 128 + o, dd * accD[i][q]);
                float cc = y0 * accC[i][q];
                atomicAdd(agg1 + (rn*256 + 128 + o)*3 + 0, x1x * cc);
                atomicAdd(agg1 + (rn*256 + 128 + o)*3 + 1, x1y * cc);
                atomicAdd(agg1 + (rn*256 + 128 + o)*3 + 2, x1z * cc);
            }
        }
    }
}

// ---------------- Kernel 3: output transform ----------------
__global__ __launch_bounds__(256) void output_transform(
    const float* __restrict__ agg0,
    const float* __restrict__ agg1,
    const float* __restrict__ Wout0,
    const float* __restrict__ Wout1,
    float* __restrict__ out)
{
    __shared__ float a0s[8 * 256];
    __shared__ float a1s[8 * 768];
    const int t = threadIdx.x;
    const int bn = blockIdx.x * 8;

    for (int i = t; i < 8 * 256; i += 256) a0s[i] = agg0[(size_t)bn*256 + i];
    for (int i = t; i < 8 * 768; i += 256) a1s[i] = agg1[(size_t)bn*768 + i];
    __syncthreads();

    const int tn = t >> 5, to = t & 31;
    const int n = bn + tn;

    float o0[4] = {0.f,0.f,0.f,0.f};
    float o1[4][3] = {};

    for (int m = 0; m < 256; ++m) {
        float a0v = a0s[tn*256 + m];
        float ax = a1s[tn*768 + m*3 + 0];
        float ay = a1s[tn*768 + m*3 + 1];
        float az = a1s[tn*768 + m*3 + 2];
        #pragma unroll
        for (int q = 0; q < 4; ++q) {
            int o = to + 32*q;
            float w0 = Wout0[m*128 + o];
            float w1 = Wout1[m*128 + o];
            o0[q] = fmaf(a0v, w0, o0[q]);
            o1[q][0] = fmaf(ax, w1, o1[q][0]);
            o1[q][1] = fmaf(ay, w1, o1[q][1]);
            o1[q][2] = fmaf(az, w1, o1[q][2]);
        }
    }
    const float scale = 0.00390625f; // 1/(sqrt(256)*16)
    #pragma unroll
    for (int q = 0; q < 4; ++q) {
        int o = to + 32*q;
        float4 v = make_float4(o0[q]*scale, o1[q][0]*scale, o1[q][1]*scale, o1[q][2]*scale);
        *(float4*)(out + ((size_t)n*128 + o)*4) = v;
    }
}

extern "C" void kernel_launch(void* const* d_in, const int* in_sizes, int n_in,
                              void* d_out, int out_size, void* d_ws, size_t ws_size,
                              hipStream_t stream) {
    const float* node_feats = (const float*)d_in[0];
    const float* edge_attrs = (const float*)d_in[1];
    const float* edge_feats = (const float*)d_in[2];
    const float* lengths    = (const float*)d_in[3];
    const int*   edge_index = (const int*)d_in[4];
    const float* W_scalar   = (const float*)d_in[5];
    const float* W_up0      = (const float*)d_in[6];
    const float* W_up1      = (const float*)d_in[7];
    const float* W1         = (const float*)d_in[8];
    const float* b1         = (const float*)d_in[9];
    const float* W2         = (const float*)d_in[10];
    const float* b2         = (const float*)d_in[11];
    const float* W3         = (const float*)d_in[12];
    const float* Wout0      = (const float*)d_in[13];
    const float* Wout1      = (const float*)d_in[14];

    float* ws = (float*)d_ws;
    float* scalars = ws;                      // N*128   = 1,280,000
    float* h0      = ws + 1280000;            // N*128
    float* h1      = ws + 2560000;            // N*128*3 = 3,840,000
    float* agg0    = ws + 6400000;            // N*256   = 2,560,000
    float* agg1    = ws + 8960000;            // N*768   = 7,680,000
    // total 16,640,000 floats = 66.56 MB
    if (ws_size < 16640000ull * 4ull) return;

    hipMemsetAsync(agg0, 0, 10240000ull * 4ull, stream);
    node_transform<<<1250, 256, 0, stream>>>(node_feats, W_scalar, W_up0, W_up1, scalars, h0, h1);
    edge_kernel<<<2500, 256, 0, stream>>>(scalars, h0, h1, edge_attrs, edge_feats, lengths,
                                          edge_index, W1, b1, W2, b2, W3, agg0, agg1);
    output_transform<<<1250, 256, 0, stream>>>(agg0, agg1, Wout0, Wout1, (float*)d_out);
}

// Round 2
// 996.108 us; speedup vs baseline: 2.0551x; 2.0551x over previous
//
#include <hip/hip_runtime.h>

#define NN 10000
#define NE 160000
#define TILE 32
#define RS 33        // LDS row stride (32 edges + 1 pad)
#define IN_ROWS 137  // reused input region rows; h lives at rows 137..264

__device__ __forceinline__ float silu_f(float x) {
    return x / (1.0f + __expf(-x));
}

// ---------------- Kernel 1: node transform ----------------
// scalars = x0 @ W_scalar * inv ; h0 = x0 @ W_up0 * inv ;
// h1t[c][n][o] = sum_m x1[n][m][c] W_up1[m][o] * inv   (c-plane transposed)
__global__ __launch_bounds__(256) void node_transform(
    const float* __restrict__ node_feats,
    const float* __restrict__ W_scalar,
    const float* __restrict__ W_up0,
    const float* __restrict__ W_up1,
    float* __restrict__ scalars,
    float* __restrict__ h0,
    float* __restrict__ h1t)
{
    __shared__ float xs[8 * 512];
    const int t = threadIdx.x;
    const int bn = blockIdx.x * 8;

    const float4* src = (const float4*)(node_feats + (size_t)bn * 512);
    float4* dst = (float4*)xs;
    #pragma unroll
    for (int i = 0; i < 4; ++i) dst[t + 256 * i] = src[t + 256 * i];
    __syncthreads();

    const int tn = t >> 5;      // 0..7 node in tile
    const int to = t & 31;      // 0..31
    const int n = bn + tn;

    float sc[4] = {0.f,0.f,0.f,0.f};
    float a0[4] = {0.f,0.f,0.f,0.f};
    float a1[4][3] = {};

    const float* x0 = xs + tn * 512;
    const float* x1 = xs + tn * 512 + 128;

    for (int k = 0; k < 128; ++k) {
        float xv = x0[k];
        float xa = x1[k*3+0], xb = x1[k*3+1], xc = x1[k*3+2];
        #pragma unroll
        for (int q = 0; q < 4; ++q) {
            int o = to + 32 * q;
            float wsc = W_scalar[k*128 + o];
            float w0  = W_up0[k*128 + o];
            float w1  = W_up1[k*128 + o];
            sc[q] = fmaf(xv, wsc, sc[q]);
            a0[q] = fmaf(xv, w0,  a0[q]);
            a1[q][0] = fmaf(xa, w1, a1[q][0]);
            a1[q][1] = fmaf(xb, w1, a1[q][1]);
            a1[q][2] = fmaf(xc, w1, a1[q][2]);
        }
    }
    const float inv = 0.08838834764831845f; // 1/sqrt(128)
    #pragma unroll
    for (int q = 0; q < 4; ++q) {
        int o = to + 32 * q;
        scalars[n*128 + o] = sc[q] * inv;
        h0[n*128 + o]      = a0[q] * inv;
        h1t[0*NN*128 + n*128 + o] = a1[q][0] * inv;
        h1t[1*NN*128 + n*128 + o] = a1[q][1] * inv;
        h1t[2*NN*128 + n*128 + o] = a1[q][2] * inv;
    }
}

// ---------------- Kernel 2: edge MLP + tensor product + atomic scatter ----------------
__global__ __launch_bounds__(256, 4) void edge_kernel(
    const float* __restrict__ scalars,
    const float* __restrict__ h0g,
    const float* __restrict__ h1t,
    const float* __restrict__ edge_attrs,
    const float* __restrict__ edge_feats,
    const float* __restrict__ lengths,
    const int* __restrict__ edge_index,
    const float* __restrict__ W1, const float* __restrict__ b1,
    const float* __restrict__ W2, const float* __restrict__ b2,
    const float* __restrict__ W3,
    float* __restrict__ agg0, float* __restrict__ agg1t)
{
    __shared__ float smem[(IN_ROWS + 128) * RS]; // input/h2 region (rows 0..136) + h region (137..264)
    __shared__ int   s_s[TILE];
    __shared__ int   r_s[TILE];
    __shared__ float4 y_s[TILE];

    const int t = threadIdx.x;
    const int e0 = blockIdx.x * TILE;

    if (t < TILE) {
        s_s[t] = edge_index[e0 + t];
        r_s[t] = edge_index[NE + e0 + t];
        y_s[t] = *(const float4*)(edge_attrs + (size_t)(e0 + t) * 4);
    }
    __syncthreads();

    // ---- stage sender scalars into rows 0..127 ----
    {
        const int e = t >> 3, j = t & 7;
        const float4* srow = (const float4*)(scalars + (size_t)s_s[e] * 128);
        #pragma unroll
        for (int m = 0; m < 4; ++m) {
            int k4 = j + 8 * m;
            float4 v = srow[k4];
            int k = 4 * k4;
            smem[(k+0)*RS + e] = v.x; smem[(k+1)*RS + e] = v.y;
            smem[(k+2)*RS + e] = v.z; smem[(k+3)*RS + e] = v.w;
        }
    }
    __syncthreads();

    const int to = t & 31;   // output lane 0..31
    const int eg = t >> 5;   // edge group 0..7
    const int eb = eg * 4;   // 4 edges per thread

    float acc1[4][4] = {};   // [edge][q]

    // ---- layer 1 part 1: k = 0..127 (sender scalars) ----
    for (int k = 0; k < 128; ++k) {
        float w[4];
        #pragma unroll
        for (int q = 0; q < 4; ++q) w[q] = W1[k*128 + to + 32*q];
        #pragma unroll
        for (int i = 0; i < 4; ++i) {
            float v = smem[k*RS + eb + i];
            #pragma unroll
            for (int q = 0; q < 4; ++q) acc1[i][q] = fmaf(v, w[q], acc1[i][q]);
        }
    }
    __syncthreads();

    // ---- restage rows 0..136: receiver scalars, edge_feats, lengths ----
    {
        const int e = t >> 3, j = t & 7;
        const float4* rrow = (const float4*)(scalars + (size_t)r_s[e] * 128);
        #pragma unroll
        for (int m = 0; m < 4; ++m) {
            int k4 = j + 8 * m;
            float4 v = rrow[k4];
            int k = 4 * k4;
            smem[(k+0)*RS + e] = v.x; smem[(k+1)*RS + e] = v.y;
            smem[(k+2)*RS + e] = v.z; smem[(k+3)*RS + e] = v.w;
        }
        smem[(128 + j)*RS + e] = edge_feats[(size_t)(e0 + e) * 8 + j];
        if (t < TILE) smem[136*RS + t] = lengths[e0 + t];
    }
    __syncthreads();

    // ---- layer 1 part 2: global k = 128..264 -> rows 0..136 ----
    for (int k = 0; k < IN_ROWS; ++k) {
        float w[4];
        #pragma unroll
        for (int q = 0; q < 4; ++q) w[q] = W1[(128 + k)*128 + to + 32*q];
        #pragma unroll
        for (int i = 0; i < 4; ++i) {
            float v = smem[k*RS + eb + i];
            #pragma unroll
            for (int q = 0; q < 4; ++q) acc1[i][q] = fmaf(v, w[q], acc1[i][q]);
        }
    }
    // bias + silu -> h region (rows 137..264)
    #pragma unroll
    for (int q = 0; q < 4; ++q) {
        float bb = b1[to + 32*q];
        #pragma unroll
        for (int i = 0; i < 4; ++i)
            smem[(IN_ROWS + to + 32*q)*RS + eb + i] = silu_f(acc1[i][q] + bb);
    }
    __syncthreads();

    // ---- layer 2: (32,128)@(128,128), h -> h2 (rows 0..127, aliased) ----
    {
        float acc[4][4] = {};
        for (int k = 0; k < 128; ++k) {
            float w[4];
            #pragma unroll
            for (int q = 0; q < 4; ++q) w[q] = W2[k*128 + to + 32*q];
            #pragma unroll
            for (int i = 0; i < 4; ++i) {
                float v = smem[(IN_ROWS + k)*RS + eb + i];
                #pragma unroll
                for (int q = 0; q < 4; ++q) acc[i][q] = fmaf(v, w[q], acc[i][q]);
            }
        }
        __syncthreads(); // everyone done reading h before overwriting? (h2 region is rows 0..127 — distinct from h rows; barrier still needed before readers of h2 below)
        #pragma unroll
        for (int q = 0; q < 4; ++q) {
            float bb = b2[to + 32*q];
            #pragma unroll
            for (int i = 0; i < 4; ++i)
                smem[(to + 32*q)*RS + eb + i] = silu_f(acc[i][q] + bb);
        }
    }
    __syncthreads();

    // ---- layer 3: four 16-acc passes over h2 (rows 0..127) ----
    const float rs3 = 0.57735026918962576f; // 1/sqrt(3)

    // pass A (W3 cols 0..127): m0A = xs0*y0*wA -> agg0[:,0:128]
    {
        float acc[4][4] = {};
        for (int k = 0; k < 128; ++k) {
            float w[4];
            #pragma unroll
            for (int q = 0; q < 4; ++q) w[q] = W3[k*512 + to + 32*q];
            #pragma unroll
            for (int i = 0; i < 4; ++i) {
                float v = smem[k*RS + eb + i];
                #pragma unroll
                for (int q = 0; q < 4; ++q) acc[i][q] = fmaf(v, w[q], acc[i][q]);
            }
        }
        #pragma unroll
        for (int i = 0; i < 4; ++i) {
            int e = eb + i;
            int sn = s_s[e], rn = r_s[e];
            float y0 = y_s[e].x;
            #pragma unroll
            for (int q = 0; q < 4; ++q) {
                int o = to + 32*q;
                float xs0 = h0g[sn*128 + o];
                atomicAdd(agg0 + (size_t)rn*256 + o, xs0 * y0 * acc[i][q]);
            }
        }
    }

    // pass B (W3 cols 256..383): mB = xs0 * y1 * wB -> agg1t[c][:,0:128]
    {
        float acc[4][4] = {};
        for (int k = 0; k < 128; ++k) {
            float w[4];
            #pragma unroll
            for (int q = 0; q < 4; ++q) w[q] = W3[k*512 + 256 + to + 32*q];
            #pragma unroll
            for (int i = 0; i < 4; ++i) {
                float v = smem[k*RS + eb + i];
                #pragma unroll
                for (int q = 0; q < 4; ++q) acc[i][q] = fmaf(v, w[q], acc[i][q]);
            }
        }
        #pragma unroll
        for (int i = 0; i < 4; ++i) {
            int e = eb + i;
            int sn = s_s[e], rn = r_s[e];
            float4 y = y_s[e];
            #pragma unroll
            for (int q = 0; q < 4; ++q) {
                int o = to + 32*q;
                float xb = h0g[sn*128 + o] * acc[i][q];
                atomicAdd(agg1t + 0*(size_t)NN*256 + (size_t)rn*256 + o, xb * y.y);
                atomicAdd(agg1t + 1*(size_t)NN*256 + (size_t)rn*256 + o, xb * y.z);
                atomicAdd(agg1t + 2*(size_t)NN*256 + (size_t)rn*256 + o, xb * y.w);
            }
        }
    }

    // pass D (W3 cols 128..255): mD = (x1.y1)/sqrt3 * wD -> agg0[:,128:256]
    {
        float acc[4][4] = {};
        for (int k = 0; k < 128; ++k) {
            float w[4];
            #pragma unroll
            for (int q = 0; q < 4; ++q) w[q] = W3[k*512 + 128 + to + 32*q];
            #pragma unroll
            for (int i = 0; i < 4; ++i) {
                float v = smem[k*RS + eb + i];
                #pragma unroll
                for (int q = 0; q < 4; ++q) acc[i][q] = fmaf(v, w[q], acc[i][q]);
            }
        }
        #pragma unroll
        for (int i = 0; i < 4; ++i) {
            int e = eb + i;
            int sn = s_s[e], rn = r_s[e];
            float4 y = y_s[e];
            #pragma unroll
            for (int q = 0; q < 4; ++q) {
                int o = to + 32*q;
                float x1x = h1t[0*NN*128 + sn*128 + o];
                float x1y = h1t[1*NN*128 + sn*128 + o];
                float x1z = h1t[2*NN*128 + sn*128 + o];
                float dd = (x1x*y.y + x1y*y.z + x1z*y.w) * rs3;
                atomicAdd(agg0 + (size_t)rn*256 + 128 + o, dd * acc[i][q]);
            }
        }
    }

    // pass C (W3 cols 384..511): mC = x1 * y0 * wC -> agg1t[c][:,128:256]
    {
        float acc[4][4] = {};
        for (int k = 0; k < 128; ++k) {
            float w[4];
            #pragma unroll
            for (int q = 0; q < 4; ++q) w[q] = W3[k*512 + 384 + to + 32*q];
            #pragma unroll
            for (int i = 0; i < 4; ++i) {
                float v = smem[k*RS + eb + i];
                #pragma unroll
                for (int q = 0; q < 4; ++q) acc[i][q] = fmaf(v, w[q], acc[i][q]);
            }
        }
        #pragma unroll
        for (int i = 0; i < 4; ++i) {
            int e = eb + i;
            int sn = s_s[e], rn = r_s[e];
            float y0 = y_s[e].x;
            #pragma unroll
            for (int q = 0; q < 4; ++q) {
                int o = to + 32*q;
                float cc = y0 * acc[i][q];
                float x1x = h1t[0*NN*128 + sn*128 + o];
                float x1y = h1t[1*NN*128 + sn*128 + o];
                float x1z = h1t[2*NN*128 + sn*128 + o];
                atomicAdd(agg1t + 0*(size_t)NN*256 + (size_t)rn*256 + 128 + o, x1x * cc);
                atomicAdd(agg1t + 1*(size_t)NN*256 + (size_t)rn*256 + 128 + o, x1y * cc);
                atomicAdd(agg1t + 2*(size_t)NN*256 + (size_t)rn*256 + 128 + o, x1z * cc);
            }
        }
    }
}

// ---------------- Kernel 3: output transform ----------------
__global__ __launch_bounds__(256) void output_transform(
    const float* __restrict__ agg0,
    const float* __restrict__ agg1t,
    const float* __restrict__ Wout0,
    const float* __restrict__ Wout1,
    float* __restrict__ out)
{
    __shared__ float a0s[8 * 256];
    __shared__ float a1s[3][8 * 256];
    const int t = threadIdx.x;
    const int bn = blockIdx.x * 8;

    for (int i = t; i < 8 * 256; i += 256) {
        a0s[i] = agg0[(size_t)bn*256 + i];
        a1s[0][i] = agg1t[0*(size_t)NN*256 + (size_t)bn*256 + i];
        a1s[1][i] = agg1t[1*(size_t)NN*256 + (size_t)bn*256 + i];
        a1s[2][i] = agg1t[2*(size_t)NN*256 + (size_t)bn*256 + i];
    }
    __syncthreads();

    const int tn = t >> 5, to = t & 31;
    const int n = bn + tn;

    float o0[4] = {0.f,0.f,0.f,0.f};
    float o1[4][3] = {};

    for (int m = 0; m < 256; ++m) {
        float a0v = a0s[tn*256 + m];
        float ax = a1s[0][tn*256 + m];
        float ay = a1s[1][tn*256 + m];
        float az = a1s[2][tn*256 + m];
        #pragma unroll
        for (int q = 0; q < 4; ++q) {
            int o = to + 32*q;
            float w0 = Wout0[m*128 + o];
            float w1 = Wout1[m*128 + o];
            o0[q] = fmaf(a0v, w0, o0[q]);
            o1[q][0] = fmaf(ax, w1, o1[q][0]);
            o1[q][1] = fmaf(ay, w1, o1[q][1]);
            o1[q][2] = fmaf(az, w1, o1[q][2]);
        }
    }
    const float scale = 0.00390625f; // 1/(sqrt(256)*16)
    #pragma unroll
    for (int q = 0; q < 4; ++q) {
        int o = to + 32*q;
        float4 v = make_float4(o0[q]*scale, o1[q][0]*scale, o1[q][1]*scale, o1[q][2]*scale);
        *(float4*)(out + ((size_t)n*128 + o)*4) = v;
    }
}

extern "C" void kernel_launch(void* const* d_in, const int* in_sizes, int n_in,
                              void* d_out, int out_size, void* d_ws, size_t ws_size,
                              hipStream_t stream) {
    const float* node_feats = (const float*)d_in[0];
    const float* edge_attrs = (const float*)d_in[1];
    const float* edge_feats = (const float*)d_in[2];
    const float* lengths    = (const float*)d_in[3];
    const int*   edge_index = (const int*)d_in[4];
    const float* W_scalar   = (const float*)d_in[5];
    const float* W_up0      = (const float*)d_in[6];
    const float* W_up1      = (const float*)d_in[7];
    const float* W1         = (const float*)d_in[8];
    const float* b1         = (const float*)d_in[9];
    const float* W2         = (const float*)d_in[10];
    const float* b2         = (const float*)d_in[11];
    const float* W3         = (const float*)d_in[12];
    const float* Wout0      = (const float*)d_in[13];
    const float* Wout1      = (const float*)d_in[14];

    float* ws = (float*)d_ws;
    float* scalars = ws;                      // N*128   = 1,280,000
    float* h0      = ws + 1280000;            // N*128
    float* h1t     = ws + 2560000;            // 3*N*128 = 3,840,000
    float* agg0    = ws + 6400000;            // N*256   = 2,560,000
    float* agg1t   = ws + 8960000;            // 3*N*256 = 7,680,000
    // total 16,640,000 floats = 66.56 MB
    if (ws_size < 16640000ull * 4ull) return;

    hipMemsetAsync(agg0, 0, 10240000ull * 4ull, stream);
    node_transform<<<1250, 256, 0, stream>>>(node_feats, W_scalar, W_up0, W_up1, scalars, h0, h1t);
    edge_kernel<<<NE / TILE, 256, 0, stream>>>(scalars, h0, h1t, edge_attrs, edge_feats, lengths,
                                               edge_index, W1, b1, W2, b2, W3, agg0, agg1t);
    output_transform<<<1250, 256, 0, stream>>>(agg0, agg1t, Wout0, Wout1, (float*)d_out);
}

// Round 3
// 712.755 us; speedup vs baseline: 2.8721x; 1.3975x over previous
//
#include <hip/hip_runtime.h>
#include <hip/hip_bf16.h>

#define NN 10000
#define NE 160000
#define TILE 32
#define A1S 296   // ushort stride, 16B-aligned rows, ~2-way bank aliasing (free)
#define A2S 136   // ushort stride for 128-col tiles

typedef __attribute__((ext_vector_type(8))) short short8;
typedef __attribute__((ext_vector_type(4))) float f32x4;

__device__ __forceinline__ float silu_f(float x) { return x / (1.0f + __expf(-x)); }
__device__ __forceinline__ unsigned short bf16u(float v) {
    __hip_bfloat16 b = __float2bfloat16(v);
    return *reinterpret_cast<unsigned short*>(&b);
}

// ---------------- Kernel 0: pack weights to bf16 fragment layout ----------------
// Wp[kt][n][kk] = W[kt*32+kk][n]  (zero-padded K for W1: 265 -> 288)
// W1p: 9*128*32 = 36864 @ 0 ; W2p: 4*128*32 = 16384 @ 36864 ; W3p: 4*512*32 = 65536 @ 53248
__global__ __launch_bounds__(256) void convert_weights(
    const float* __restrict__ W1, const float* __restrict__ W2,
    const float* __restrict__ W3, unsigned short* __restrict__ wp)
{
    int idx = blockIdx.x * 256 + threadIdx.x;
    if (idx < 36864) {
        int kt = idx >> 12, rem = idx & 4095, n = rem >> 5, kk = rem & 31;
        int k = kt * 32 + kk;
        wp[idx] = (k < 265) ? bf16u(W1[k * 128 + n]) : (unsigned short)0;
    } else if (idx < 53248) {
        int j = idx - 36864;
        int kt = j >> 12, rem = j & 4095, n = rem >> 5, kk = rem & 31;
        wp[idx] = bf16u(W2[(kt * 32 + kk) * 128 + n]);
    } else if (idx < 118784) {
        int j = idx - 53248;
        int kt = j >> 14, rem = j & 16383, n = rem >> 5, kk = rem & 31;
        wp[idx] = bf16u(W3[(kt * 32 + kk) * 512 + n]);
    }
}

// ---------------- Kernel 1: node transform ----------------
__global__ __launch_bounds__(256) void node_transform(
    const float* __restrict__ node_feats,
    const float* __restrict__ W_scalar,
    const float* __restrict__ W_up0,
    const float* __restrict__ W_up1,
    unsigned short* __restrict__ scalars_bf,
    float* __restrict__ h0,
    float* __restrict__ h1t)
{
    __shared__ float xs[8 * 512];
    const int t = threadIdx.x;
    const int bn = blockIdx.x * 8;

    const float4* src = (const float4*)(node_feats + (size_t)bn * 512);
    float4* dst = (float4*)xs;
    #pragma unroll
    for (int i = 0; i < 4; ++i) dst[t + 256 * i] = src[t + 256 * i];
    __syncthreads();

    const int tn = t >> 5, to = t & 31;
    const int n = bn + tn;

    float sc[4] = {0.f,0.f,0.f,0.f};
    float a0[4] = {0.f,0.f,0.f,0.f};
    float a1[4][3] = {};

    const float* x0 = xs + tn * 512;
    const float* x1 = xs + tn * 512 + 128;

    for (int k = 0; k < 128; ++k) {
        float xv = x0[k];
        float xa = x1[k*3+0], xb = x1[k*3+1], xc = x1[k*3+2];
        #pragma unroll
        for (int q = 0; q < 4; ++q) {
            int o = to + 32 * q;
            sc[q] = fmaf(xv, W_scalar[k*128 + o], sc[q]);
            a0[q] = fmaf(xv, W_up0[k*128 + o],  a0[q]);
            float w1 = W_up1[k*128 + o];
            a1[q][0] = fmaf(xa, w1, a1[q][0]);
            a1[q][1] = fmaf(xb, w1, a1[q][1]);
            a1[q][2] = fmaf(xc, w1, a1[q][2]);
        }
    }
    const float inv = 0.08838834764831845f; // 1/sqrt(128)
    #pragma unroll
    for (int q = 0; q < 4; ++q) {
        int o = to + 32 * q;
        scalars_bf[n*128 + o] = bf16u(sc[q] * inv);
        h0[n*128 + o]         = a0[q] * inv;
        h1t[0*NN*128 + n*128 + o] = a1[q][0] * inv;
        h1t[1*NN*128 + n*128 + o] = a1[q][1] * inv;
        h1t[2*NN*128 + n*128 + o] = a1[q][2] * inv;
    }
}

// ---------------- Kernel 2: MFMA edge MLP + tensor product + atomic scatter ----------------
__global__ __launch_bounds__(256, 4) void edge_kernel(
    const unsigned short* __restrict__ scalars_bf,
    const float* __restrict__ h0g,
    const float* __restrict__ h1t,
    const float* __restrict__ edge_attrs,
    const float* __restrict__ edge_feats,
    const float* __restrict__ lengths,
    const int* __restrict__ edge_index,
    const float* __restrict__ b1, const float* __restrict__ b2,
    const unsigned short* __restrict__ wp,
    float* __restrict__ agg0, float* __restrict__ agg1t)
{
    __shared__ unsigned short A1[TILE * A1S];   // mlp_in bf16 (layer1 A); reused as A3 (h2) stride A2S
    __shared__ unsigned short A2[TILE * A2S];   // h bf16 (layer2 A)
    __shared__ int   s_s[TILE];
    __shared__ int   r_s[TILE];
    __shared__ float4 y_s[TILE];

    const int t = threadIdx.x;
    const int e0 = blockIdx.x * TILE;
    const int wv = t >> 6;          // wave 0..3
    const int lane = t & 63;
    const int l16 = lane & 15;
    const int l4 = lane >> 4;

    if (t < TILE) {
        s_s[t] = edge_index[e0 + t];
        r_s[t] = edge_index[NE + e0 + t];
        y_s[t] = *(const float4*)(edge_attrs + (size_t)(e0 + t) * 4);
    }
    __syncthreads();

    // ---- stage mlp_in (bf16) into A1: cols 0..127 sender, 128..255 receiver, 256..263 ef, 264 len, 265..287 zero
    {
        const int e = t >> 3, j = t & 7;      // 8 threads/edge, 16 cols each
        const unsigned short* srow = scalars_bf + (size_t)s_s[e] * 128;
        const unsigned short* rrow = scalars_bf + (size_t)r_s[e] * 128;
        *(uint4*)(A1 + e*A1S + j*16)       = *(const uint4*)(srow + j*16);
        *(uint4*)(A1 + e*A1S + j*16 + 8)   = *(const uint4*)(srow + j*16 + 8);
        *(uint4*)(A1 + e*A1S + 128 + j*16)     = *(const uint4*)(rrow + j*16);
        *(uint4*)(A1 + e*A1S + 128 + j*16 + 8) = *(const uint4*)(rrow + j*16 + 8);
        A1[e*A1S + 256 + j] = bf16u(edge_feats[(size_t)(e0 + e) * 8 + j]);
        if (t < TILE) A1[t*A1S + 264] = bf16u(lengths[e0 + t]);
        for (int i = t; i < TILE * 23; i += 256) {
            int row = i / 23, c = 265 + (i - row * 23);
            A1[row*A1S + c] = 0;
        }
    }
    __syncthreads();

    const unsigned short* Wp1 = wp;
    const unsigned short* Wp2 = wp + 36864;
    const unsigned short* Wp3 = wp + 53248;

    // ---- layer 1: (32 x 288) @ (288 x 128) ----
    {
        f32x4 acc[2][2] = {};
        for (int kt = 0; kt < 9; ++kt) {
            short8 a0 = *(const short8*)(A1 + (     l16)*A1S + kt*32 + l4*8);
            short8 a1 = *(const short8*)(A1 + (16 + l16)*A1S + kt*32 + l4*8);
            #pragma unroll
            for (int n = 0; n < 2; ++n) {
                int col = (2*wv + n)*16 + l16;
                short8 b = *(const short8*)(Wp1 + ((size_t)kt*128 + col)*32 + l4*8);
                acc[0][n] = __builtin_amdgcn_mfma_f32_16x16x32_bf16(a0, b, acc[0][n], 0, 0, 0);
                acc[1][n] = __builtin_amdgcn_mfma_f32_16x16x32_bf16(a1, b, acc[1][n], 0, 0, 0);
            }
        }
        #pragma unroll
        for (int n = 0; n < 2; ++n) {
            int col = (2*wv + n)*16 + l16;
            float bb = b1[col];
            #pragma unroll
            for (int m = 0; m < 2; ++m)
                #pragma unroll
                for (int r = 0; r < 4; ++r) {
                    int row = m*16 + l4*4 + r;
                    A2[row*A2S + col] = bf16u(silu_f(acc[m][n][r] + bb));
                }
        }
    }
    __syncthreads();

    // ---- layer 2: (32 x 128) @ (128 x 128), h2 -> A1 region (stride A2S) ----
    unsigned short* A3 = A1;
    {
        f32x4 acc[2][2] = {};
        for (int kt = 0; kt < 4; ++kt) {
            short8 a0 = *(const short8*)(A2 + (     l16)*A2S + kt*32 + l4*8);
            short8 a1 = *(const short8*)(A2 + (16 + l16)*A2S + kt*32 + l4*8);
            #pragma unroll
            for (int n = 0; n < 2; ++n) {
                int col = (2*wv + n)*16 + l16;
                short8 b = *(const short8*)(Wp2 + ((size_t)kt*128 + col)*32 + l4*8);
                acc[0][n] = __builtin_amdgcn_mfma_f32_16x16x32_bf16(a0, b, acc[0][n], 0, 0, 0);
                acc[1][n] = __builtin_amdgcn_mfma_f32_16x16x32_bf16(a1, b, acc[1][n], 0, 0, 0);
            }
        }
        #pragma unroll
        for (int n = 0; n < 2; ++n) {
            int col = (2*wv + n)*16 + l16;
            float bb = b2[col];
            #pragma unroll
            for (int m = 0; m < 2; ++m)
                #pragma unroll
                for (int r = 0; r < 4; ++r) {
                    int row = m*16 + l4*4 + r;
                    A3[row*A2S + col] = bf16u(silu_f(acc[m][n][r] + bb));
                }
        }
    }
    __syncthreads();

    // ---- layer 3: (32 x 128) @ (128 x 512); wave wv owns W3 cols [wv*128, wv*128+128)
    // wv=0 -> chunk A, wv=1 -> chunk D, wv=2 -> chunk B, wv=3 -> chunk C. Two 64-col halves.
    const float rs3 = 0.57735026918962576f; // 1/sqrt(3)
    for (int hh = 0; hh < 2; ++hh) {
        f32x4 acc[2][4] = {};
        for (int kt = 0; kt < 4; ++kt) {
            short8 a0 = *(const short8*)(A3 + (     l16)*A2S + kt*32 + l4*8);
            short8 a1 = *(const short8*)(A3 + (16 + l16)*A2S + kt*32 + l4*8);
            #pragma unroll
            for (int n = 0; n < 4; ++n) {
                int col = wv*128 + hh*64 + n*16 + l16;
                short8 b = *(const short8*)(Wp3 + ((size_t)kt*512 + col)*32 + l4*8);
                acc[0][n] = __builtin_amdgcn_mfma_f32_16x16x32_bf16(a0, b, acc[0][n], 0, 0, 0);
                acc[1][n] = __builtin_amdgcn_mfma_f32_16x16x32_bf16(a1, b, acc[1][n], 0, 0, 0);
            }
        }
        // scatter: lane holds cols o' = hh*64 + n*16 + l16 (within the 128-dim chunk), rows m*16+l4*4+r
        #pragma unroll
        for (int m = 0; m < 2; ++m) {
            #pragma unroll
            for (int r = 0; r < 4; ++r) {
                int e = m*16 + l4*4 + r;
                int sn = s_s[e], rn = r_s[e];
                float4 y = y_s[e];
                if (wv == 0) {        // A: xs0*y0*wA -> agg0[:, 0:128]
                    #pragma unroll
                    for (int n = 0; n < 4; ++n) {
                        int o = hh*64 + n*16 + l16;
                        float xs0 = h0g[(size_t)sn*128 + o];
                        atomicAdd(agg0 + (size_t)rn*256 + o, xs0 * y.x * acc[m][n][r]);
                    }
                } else if (wv == 1) { // D: (x1.y1)/sqrt3*wD -> agg0[:, 128:256]
                    #pragma unroll
                    for (int n = 0; n < 4; ++n) {
                        int o = hh*64 + n*16 + l16;
                        float xx = h1t[0*NN*128 + sn*128 + o];
                        float xy = h1t[1*NN*128 + sn*128 + o];
                        float xz = h1t[2*NN*128 + sn*128 + o];
                        float dd = (xx*y.y + xy*y.z + xz*y.w) * rs3;
                        atomicAdd(agg0 + (size_t)rn*256 + 128 + o, dd * acc[m][n][r]);
                    }
                } else if (wv == 2) { // B: xs0*y1*wB -> agg1t[c][:, 0:128]
                    #pragma unroll
                    for (int n = 0; n < 4; ++n) {
                        int o = hh*64 + n*16 + l16;
                        float xb = h0g[(size_t)sn*128 + o] * acc[m][n][r];
                        atomicAdd(agg1t + 0*(size_t)NN*256 + (size_t)rn*256 + o, xb * y.y);
                        atomicAdd(agg1t + 1*(size_t)NN*256 + (size_t)rn*256 + o, xb * y.z);
                        atomicAdd(agg1t + 2*(size_t)NN*256 + (size_t)rn*256 + o, xb * y.w);
                    }
                } else {              // C: x1*y0*wC -> agg1t[c][:, 128:256]
                    #pragma unroll
                    for (int n = 0; n < 4; ++n) {
                        int o = hh*64 + n*16 + l16;
                        float cc = y.x * acc[m][n][r];
                        float xx = h1t[0*NN*128 + sn*128 + o];
                        float xy = h1t[1*NN*128 + sn*128 + o];
                        float xz = h1t[2*NN*128 + sn*128 + o];
                        atomicAdd(agg1t + 0*(size_t)NN*256 + (size_t)rn*256 + 128 + o, xx * cc);
                        atomicAdd(agg1t + 1*(size_t)NN*256 + (size_t)rn*256 + 128 + o, xy * cc);
                        atomicAdd(agg1t + 2*(size_t)NN*256 + (size_t)rn*256 + 128 + o, xz * cc);
                    }
                }
            }
        }
    }
}

// ---------------- Kernel 3: output transform ----------------
__global__ __launch_bounds__(256) void output_transform(
    const float* __restrict__ agg0,
    const float* __restrict__ agg1t,
    const float* __restrict__ Wout0,
    const float* __restrict__ Wout1,
    float* __restrict__ out)
{
    __shared__ float a0s[8 * 256];
    __shared__ float a1s[3][8 * 256];
    const int t = threadIdx.x;
    const int bn = blockIdx.x * 8;

    for (int i = t; i < 8 * 256; i += 256) {
        a0s[i] = agg0[(size_t)bn*256 + i];
        a1s[0][i] = agg1t[0*(size_t)NN*256 + (size_t)bn*256 + i];
        a1s[1][i] = agg1t[1*(size_t)NN*256 + (size_t)bn*256 + i];
        a1s[2][i] = agg1t[2*(size_t)NN*256 + (size_t)bn*256 + i];
    }
    __syncthreads();

    const int tn = t >> 5, to = t & 31;
    const int n = bn + tn;

    float o0[4] = {0.f,0.f,0.f,0.f};
    float o1[4][3] = {};

    for (int m = 0; m < 256; ++m) {
        float a0v = a0s[tn*256 + m];
        float ax = a1s[0][tn*256 + m];
        float ay = a1s[1][tn*256 + m];
        float az = a1s[2][tn*256 + m];
        #pragma unroll
        for (int q = 0; q < 4; ++q) {
            int o = to + 32*q;
            float w0 = Wout0[m*128 + o];
            float w1 = Wout1[m*128 + o];
            o0[q] = fmaf(a0v, w0, o0[q]);
            o1[q][0] = fmaf(ax, w1, o1[q][0]);
            o1[q][1] = fmaf(ay, w1, o1[q][1]);
            o1[q][2] = fmaf(az, w1, o1[q][2]);
        }
    }
    const float scale = 0.00390625f; // 1/(sqrt(256)*16)
    #pragma unroll
    for (int q = 0; q < 4; ++q) {
        int o = to + 32*q;
        float4 v = make_float4(o0[q]*scale, o1[q][0]*scale, o1[q][1]*scale, o1[q][2]*scale);
        *(float4*)(out + ((size_t)n*128 + o)*4) = v;
    }
}

extern "C" void kernel_launch(void* const* d_in, const int* in_sizes, int n_in,
                              void* d_out, int out_size, void* d_ws, size_t ws_size,
                              hipStream_t stream) {
    const float* node_feats = (const float*)d_in[0];
    const float* edge_attrs = (const float*)d_in[1];
    const float* edge_feats = (const float*)d_in[2];
    const float* lengths    = (const float*)d_in[3];
    const int*   edge_index = (const int*)d_in[4];
    const float* W_scalar   = (const float*)d_in[5];
    const float* W_up0      = (const float*)d_in[6];
    const float* W_up1      = (const float*)d_in[7];
    const float* W1         = (const float*)d_in[8];
    const float* b1         = (const float*)d_in[9];
    const float* W2         = (const float*)d_in[10];
    const float* b2         = (const float*)d_in[11];
    const float* W3         = (const float*)d_in[12];
    const float* Wout0      = (const float*)d_in[13];
    const float* Wout1      = (const float*)d_in[14];

    float* ws = (float*)d_ws;
    unsigned short* scalars_bf = (unsigned short*)ws;      // N*128 bf16 = 640,000 f32 slots
    float* h0    = ws + 640000;                            // N*128
    float* h1t   = ws + 1920000;                           // 3*N*128
    float* agg0  = ws + 5760000;                           // N*256
    float* agg1t = ws + 8320000;                           // 3*N*256
    unsigned short* wpack = (unsigned short*)(ws + 16000000); // 118784 bf16 = 59392 f32 slots
    if (ws_size < 16059392ull * 4ull) return;

    hipMemsetAsync(agg0, 0, 10240000ull * 4ull, stream);
    convert_weights<<<464, 256, 0, stream>>>(W1, W2, W3, wpack);
    node_transform<<<1250, 256, 0, stream>>>(node_feats, W_scalar, W_up0, W_up1, scalars_bf, h0, h1t);
    edge_kernel<<<NE / TILE, 256, 0, stream>>>(scalars_bf, h0, h1t, edge_attrs, edge_feats, lengths,
                                               edge_index, b1, b2, wpack, agg0, agg1t);
    output_transform<<<1250, 256, 0, stream>>>(agg0, agg1t, Wout0, Wout1, (float*)d_out);
}

// Round 5
// 407.201 us; speedup vs baseline: 5.0272x; 1.7504x over previous
//
#include <hip/hip_runtime.h>
#include <hip/hip_bf16.h>

#define NN 10000
#define NE 160000
#define TILE 32
#define A1S 296   // ushort stride for 288-col staging tile
#define A2S 136   // ushort stride for 128-col tiles

typedef __attribute__((ext_vector_type(8))) short short8;
typedef __attribute__((ext_vector_type(4))) float f32x4;

__device__ __forceinline__ float silu_f(float x) { return x / (1.0f + __expf(-x)); }
__device__ __forceinline__ unsigned short bf16u(float v) {
    __hip_bfloat16 b = __float2bfloat16(v);
    return *reinterpret_cast<unsigned short*>(&b);
}

// ---------------- Kernel 0: pack weights to bf16 fragment layout ----------------
__global__ __launch_bounds__(256) void convert_weights(
    const float* __restrict__ W1, const float* __restrict__ W2,
    const float* __restrict__ W3, unsigned short* __restrict__ wp)
{
    int idx = blockIdx.x * 256 + threadIdx.x;
    if (idx < 36864) {
        int kt = idx >> 12, rem = idx & 4095, n = rem >> 5, kk = rem & 31;
        int k = kt * 32 + kk;
        wp[idx] = (k < 265) ? bf16u(W1[k * 128 + n]) : (unsigned short)0;
    } else if (idx < 53248) {
        int j = idx - 36864;
        int kt = j >> 12, rem = j & 4095, n = rem >> 5, kk = rem & 31;
        wp[idx] = bf16u(W2[(kt * 32 + kk) * 128 + n]);
    } else if (idx < 118784) {
        int j = idx - 53248;
        int kt = j >> 14, rem = j & 16383, n = rem >> 5, kk = rem & 31;
        wp[idx] = bf16u(W3[(kt * 32 + kk) * 512 + n]);
    }
}

// ---------------- Kernel 1: node transform ----------------
__global__ __launch_bounds__(256) void node_transform(
    const float* __restrict__ node_feats,
    const float* __restrict__ W_scalar,
    const float* __restrict__ W_up0,
    const float* __restrict__ W_up1,
    unsigned short* __restrict__ scalars_bf,
    float* __restrict__ h0,
    float* __restrict__ h1t)
{
    __shared__ float xs[8 * 512];
    const int t = threadIdx.x;
    const int bn = blockIdx.x * 8;

    const float4* src = (const float4*)(node_feats + (size_t)bn * 512);
    float4* dst = (float4*)xs;
    #pragma unroll
    for (int i = 0; i < 4; ++i) dst[t + 256 * i] = src[t + 256 * i];
    __syncthreads();

    const int tn = t >> 5, to = t & 31;
    const int n = bn + tn;

    float sc[4] = {0.f,0.f,0.f,0.f};
    float a0[4] = {0.f,0.f,0.f,0.f};
    float a1[4][3] = {};

    const float* x0 = xs + tn * 512;
    const float* x1 = xs + tn * 512 + 128;

    for (int k = 0; k < 128; ++k) {
        float xv = x0[k];
        float xa = x1[k*3+0], xb = x1[k*3+1], xc = x1[k*3+2];
        #pragma unroll
        for (int q = 0; q < 4; ++q) {
            int o = to + 32 * q;
            sc[q] = fmaf(xv, W_scalar[k*128 + o], sc[q]);
            a0[q] = fmaf(xv, W_up0[k*128 + o],  a0[q]);
            float w1 = W_up1[k*128 + o];
            a1[q][0] = fmaf(xa, w1, a1[q][0]);
            a1[q][1] = fmaf(xb, w1, a1[q][1]);
            a1[q][2] = fmaf(xc, w1, a1[q][2]);
        }
    }
    const float inv = 0.08838834764831845f; // 1/sqrt(128)
    #pragma unroll
    for (int q = 0; q < 4; ++q) {
        int o = to + 32 * q;
        scalars_bf[n*128 + o] = bf16u(sc[q] * inv);
        h0[n*128 + o]         = a0[q] * inv;
        h1t[0*NN*128 + n*128 + o] = a1[q][0] * inv;
        h1t[1*NN*128 + n*128 + o] = a1[q][1] * inv;
        h1t[2*NN*128 + n*128 + o] = a1[q][2] * inv;
    }
}

// ---------------- CSR build ----------------
__global__ __launch_bounds__(256) void hist_kernel(const int* __restrict__ edge_index,
                                                   int* __restrict__ deg) {
    int e = blockIdx.x * 256 + threadIdx.x;
    if (e < NE) atomicAdd(&deg[edge_index[NE + e]], 1);
}

// blocked exclusive scan of deg[0..NN) -> cursor, single block, 40 elems/thread
__global__ __launch_bounds__(256) void scan_kernel(const int* __restrict__ deg,
                                                   int* __restrict__ cursor) {
    __shared__ int s[256];
    const int t = threadIdx.x;
    const int base = t * 40;
    int ld[40];
    int lsum = 0;
    #pragma unroll
    for (int i = 0; i < 40; ++i) {
        int idx = base + i;
        ld[i] = (idx < NN) ? deg[idx] : 0;
        lsum += ld[i];
    }
    s[t] = lsum;
    __syncthreads();
    for (int off = 1; off < 256; off <<= 1) {
        int u = (t >= off) ? s[t - off] : 0;
        __syncthreads();
        s[t] += u;
        __syncthreads();
    }
    int run = s[t] - lsum;   // exclusive prefix of this thread's chunk
    #pragma unroll
    for (int i = 0; i < 40; ++i) {
        int idx = base + i;
        if (idx < NN) cursor[idx] = run;
        run += ld[i];
    }
}

__global__ __launch_bounds__(256) void perm_kernel(const int* __restrict__ edge_index,
                                                   int* __restrict__ cursor,
                                                   int* __restrict__ perm) {
    int e = blockIdx.x * 256 + threadIdx.x;
    if (e < NE) {
        int r = edge_index[NE + e];
        int pos = atomicAdd(&cursor[r], 1);
        perm[pos] = e;
    }
}

// ---------------- Kernel 2: MFMA edge MLP + TP + run-merged sorted scatter ----------------
__global__ __launch_bounds__(256, 3) void edge_kernel(
    const unsigned short* __restrict__ scalars_bf,
    const float* __restrict__ h0g,
    const float* __restrict__ h1t,
    const float* __restrict__ edge_attrs,
    const float* __restrict__ edge_feats,
    const float* __restrict__ lengths,
    const int* __restrict__ edge_index,
    const int* __restrict__ perm,
    const float* __restrict__ b1, const float* __restrict__ b2,
    const unsigned short* __restrict__ wp,
    float* __restrict__ agg0, float* __restrict__ agg1t)
{
    // LDS union: A1 [0,18944) stride A1S; A2 [18944,27648) stride A2S;
    // A3 = A1 region, stride A2S -> occupies [0,8704); PKf fp32 [32][256] at [8704,41472).
    __shared__ unsigned char smem_u[41472];
    __shared__ int   eid_s[TILE];
    __shared__ int   s_s[TILE];
    __shared__ int   r_s[TILE];
    __shared__ float4 y_s[TILE];

    unsigned short* A1 = (unsigned short*)smem_u;
    unsigned short* A2 = (unsigned short*)(smem_u + 18944);
    unsigned short* A3 = A1;
    float* PKf = (float*)(smem_u + 8704);

    const int t = threadIdx.x;
    const int e0 = blockIdx.x * TILE;
    const int wv = t >> 6;          // wave 0..3
    const int lane = t & 63;
    const int l16 = lane & 15;
    const int l4 = lane >> 4;

    if (t < TILE) {
        int eid = perm[e0 + t];
        eid_s[t] = eid;
        s_s[t] = edge_index[eid];
        r_s[t] = edge_index[NE + eid];
        y_s[t] = *(const float4*)(edge_attrs + (size_t)eid * 4);
    }
    __syncthreads();

    // ---- stage mlp_in (bf16) into A1 ----
    {
        const int e = t >> 3, j = t & 7;
        const unsigned short* srow = scalars_bf + (size_t)s_s[e] * 128;
        const unsigned short* rrow = scalars_bf + (size_t)r_s[e] * 128;
        *(uint4*)(A1 + e*A1S + j*16)       = *(const uint4*)(srow + j*16);
        *(uint4*)(A1 + e*A1S + j*16 + 8)   = *(const uint4*)(srow + j*16 + 8);
        *(uint4*)(A1 + e*A1S + 128 + j*16)     = *(const uint4*)(rrow + j*16);
        *(uint4*)(A1 + e*A1S + 128 + j*16 + 8) = *(const uint4*)(rrow + j*16 + 8);
        A1[e*A1S + 256 + j] = bf16u(edge_feats[(size_t)eid_s[e] * 8 + j]);
        if (t < TILE) A1[t*A1S + 264] = bf16u(lengths[eid_s[t]]);
        for (int i = t; i < TILE * 23; i += 256) {
            int row = i / 23, c = 265 + (i - row * 23);
            A1[row*A1S + c] = 0;
        }
    }
    __syncthreads();

    const unsigned short* Wp1 = wp;
    const unsigned short* Wp2 = wp + 36864;
    const unsigned short* Wp3 = wp + 53248;

    // ---- layer 1: (32 x 288) @ (288 x 128) ----
    {
        f32x4 acc[2][2] = {};
        for (int kt = 0; kt < 9; ++kt) {
            short8 a0 = *(const short8*)(A1 + (     l16)*A1S + kt*32 + l4*8);
            short8 a1 = *(const short8*)(A1 + (16 + l16)*A1S + kt*32 + l4*8);
            #pragma unroll
            for (int n = 0; n < 2; ++n) {
                int col = (2*wv + n)*16 + l16;
                short8 b = *(const short8*)(Wp1 + ((size_t)kt*128 + col)*32 + l4*8);
                acc[0][n] = __builtin_amdgcn_mfma_f32_16x16x32_bf16(a0, b, acc[0][n], 0, 0, 0);
                acc[1][n] = __builtin_amdgcn_mfma_f32_16x16x32_bf16(a1, b, acc[1][n], 0, 0, 0);
            }
        }
        #pragma unroll
        for (int n = 0; n < 2; ++n) {
            int col = (2*wv + n)*16 + l16;
            float bb = b1[col];
            #pragma unroll
            for (int m = 0; m < 2; ++m)
                #pragma unroll
                for (int r = 0; r < 4; ++r) {
                    int row = m*16 + l4*4 + r;
                    A2[row*A2S + col] = bf16u(silu_f(acc[m][n][r] + bb));
                }
        }
    }
    __syncthreads();

    // ---- layer 2: (32 x 128) @ (128 x 128) -> A3 (A1 region, stride A2S) ----
    {
        f32x4 acc[2][2] = {};
        for (int kt = 0; kt < 4; ++kt) {
            short8 a0 = *(const short8*)(A2 + (     l16)*A2S + kt*32 + l4*8);
            short8 a1 = *(const short8*)(A2 + (16 + l16)*A2S + kt*32 + l4*8);
            #pragma unroll
            for (int n = 0; n < 2; ++n) {
                int col = (2*wv + n)*16 + l16;
                short8 b = *(const short8*)(Wp2 + ((size_t)kt*128 + col)*32 + l4*8);
                acc[0][n] = __builtin_amdgcn_mfma_f32_16x16x32_bf16(a0, b, acc[0][n], 0, 0, 0);
                acc[1][n] = __builtin_amdgcn_mfma_f32_16x16x32_bf16(a1, b, acc[1][n], 0, 0, 0);
            }
        }
        #pragma unroll
        for (int n = 0; n < 2; ++n) {
            int col = (2*wv + n)*16 + l16;
            float bb = b2[col];
            #pragma unroll
            for (int m = 0; m < 2; ++m)
                #pragma unroll
                for (int r = 0; r < 4; ++r) {
                    int row = m*16 + l4*4 + r;
                    A3[row*A2S + col] = bf16u(silu_f(acc[m][n][r] + bb));
                }
        }
    }
    __syncthreads();   // A3 visible; A2/A1-tail now dead -> PKf may use them

    // ---- layer 3 in two passes. pass 0: chunks A(cols 0..127)+B(256..383);
    //      pass 1: D(128..255)+C(384..511). Wave wv owns 32 cols of each chunk.
    //      PKf[row][oo]: oo<128 family0 (A or D), oo>=128 family1 (B or C), fp32, folds in fp32.
    const float rs3 = 0.57735026918962576f;
    #pragma unroll
    for (int pass = 0; pass < 2; ++pass) {
        const int base0 = pass ? 128 : 0;
        const int base1 = pass ? 384 : 256;
        {
            f32x4 acc[2][4] = {};
            for (int kt = 0; kt < 4; ++kt) {
                short8 a0 = *(const short8*)(A3 + (     l16)*A2S + kt*32 + l4*8);
                short8 a1 = *(const short8*)(A3 + (16 + l16)*A2S + kt*32 + l4*8);
                #pragma unroll
                for (int n = 0; n < 4; ++n) {
                    int col = (n < 2 ? base0 : base1) + wv*32 + (n & 1)*16 + l16;
                    short8 b = *(const short8*)(Wp3 + ((size_t)kt*512 + col)*32 + l4*8);
                    acc[0][n] = __builtin_amdgcn_mfma_f32_16x16x32_bf16(a0, b, acc[0][n], 0, 0, 0);
                    acc[1][n] = __builtin_amdgcn_mfma_f32_16x16x32_bf16(a1, b, acc[1][n], 0, 0, 0);
                }
            }
            #pragma unroll
            for (int m = 0; m < 2; ++m)
                #pragma unroll
                for (int r = 0; r < 4; ++r) {
                    int row = m*16 + l4*4 + r;
                    float y0 = y_s[row].x;
                    float f0 = pass ? rs3 : y0;    // D*1/sqrt3 | A*y0
                    float f1 = pass ? y0  : 1.0f;  // C*y0      | B
                    #pragma unroll
                    for (int n = 0; n < 4; ++n) {
                        int oo = (n < 2 ? 0 : 128) + wv*32 + (n & 1)*16 + l16;
                        PKf[row*256 + oo] = acc[m][n][r] * (n < 2 ? f0 : f1);
                    }
                }
        }
        __syncthreads();

        // ---- scatter: thread t owns column o of this pass's 128-col block;
        //      halves: t<128 -> rows 0..15, t>=128 -> rows 16..31; run-merge within half ----
        {
            const int half = t >> 7;
            const int o = t & 127;
            const int rlo = half * 16, rhi = rlo + 15;
            float ac0 = 0.f, ac1 = 0.f, ac2 = 0.f, ac3 = 0.f;
            int run_start = rlo;
            int prev_rn = r_s[rlo];

            auto flush = [&](int rn, bool interior) {
                size_t b0 = (size_t)rn * 256 + base0 + o;   // base0 = 0 (A/B pass) or 128 (D/C pass)
                if (interior) {
                    agg0[b0] = ac0;
                    agg1t[0*(size_t)NN*256 + b0] = ac1;
                    agg1t[1*(size_t)NN*256 + b0] = ac2;
                    agg1t[2*(size_t)NN*256 + b0] = ac3;
                } else {
                    atomicAdd(agg0 + b0, ac0);
                    atomicAdd(agg1t + 0*(size_t)NN*256 + b0, ac1);
                    atomicAdd(agg1t + 1*(size_t)NN*256 + b0, ac2);
                    atomicAdd(agg1t + 2*(size_t)NN*256 + b0, ac3);
                }
            };

            for (int row = rlo; row <= rhi; ++row) {
                int rn = r_s[row];
                if (rn != prev_rn) {
                    flush(prev_rn, run_start > rlo);   // run end = row-1 < rhi always here
                    ac0 = ac1 = ac2 = ac3 = 0.f;
                    run_start = row;
                    prev_rn = rn;
                }
                int sn = s_s[row];
                float w0 = PKf[row*256 + o];
                float w1 = PKf[row*256 + 128 + o];
                float4 y = y_s[row];
                if (pass == 0) {
                    float x = h0g[(size_t)sn*128 + o];
                    ac0 = fmaf(x, w0, ac0);            // A (y0 folded)
                    float xb = x * w1;                 // B
                    ac1 = fmaf(xb, y.y, ac1);
                    ac2 = fmaf(xb, y.z, ac2);
                    ac3 = fmaf(xb, y.w, ac3);
                } else {
                    float xx = h1t[0*NN*128 + (size_t)sn*128 + o];
                    float xy = h1t[1*NN*128 + (size_t)sn*128 + o];
                    float xz = h1t[2*NN*128 + (size_t)sn*128 + o];
                    float dd = xx*y.y + xy*y.z + xz*y.w;  // D (1/sqrt3 folded into w0)
                    ac0 = fmaf(dd, w0, ac0);
                    ac1 = fmaf(xx, w1, ac1);           // C (y0 folded into w1)
                    ac2 = fmaf(xy, w1, ac2);
                    ac3 = fmaf(xz, w1, ac3);
                }
            }
            flush(prev_rn, false);                     // run end = rhi -> boundary, atomic
        }
        __syncthreads();   // protect PKf before next pass overwrites
    }
}

// ---------------- Kernel 3: output transform ----------------
__global__ __launch_bounds__(256) void output_transform(
    const float* __restrict__ agg0,
    const float* __restrict__ agg1t,
    const float* __restrict__ Wout0,
    const float* __restrict__ Wout1,
    float* __restrict__ out)
{
    __shared__ float a0s[8 * 256];
    __shared__ float a1s[3][8 * 256];
    const int t = threadIdx.x;
    const int bn = blockIdx.x * 8;

    for (int i = t; i < 8 * 256; i += 256) {
        a0s[i] = agg0[(size_t)bn*256 + i];
        a1s[0][i] = agg1t[0*(size_t)NN*256 + (size_t)bn*256 + i];
        a1s[1][i] = agg1t[1*(size_t)NN*256 + (size_t)bn*256 + i];
        a1s[2][i] = agg1t[2*(size_t)NN*256 + (size_t)bn*256 + i];
    }
    __syncthreads();

    const int tn = t >> 5, to = t & 31;
    const int n = bn + tn;

    float o0[4] = {0.f,0.f,0.f,0.f};
    float o1[4][3] = {};

    for (int m = 0; m < 256; ++m) {
        float a0v = a0s[tn*256 + m];
        float ax = a1s[0][tn*256 + m];
        float ay = a1s[1][tn*256 + m];
        float az = a1s[2][tn*256 + m];
        #pragma unroll
        for (int q = 0; q < 4; ++q) {
            int o = to + 32*q;
            float w0 = Wout0[m*128 + o];
            float w1 = Wout1[m*128 + o];
            o0[q] = fmaf(a0v, w0, o0[q]);
            o1[q][0] = fmaf(ax, w1, o1[q][0]);
            o1[q][1] = fmaf(ay, w1, o1[q][1]);
            o1[q][2] = fmaf(az, w1, o1[q][2]);
        }
    }
    const float scale = 0.00390625f; // 1/(sqrt(256)*16)
    #pragma unroll
    for (int q = 0; q < 4; ++q) {
        int o = to + 32*q;
        float4 v = make_float4(o0[q]*scale, o1[q][0]*scale, o1[q][1]*scale, o1[q][2]*scale);
        *(float4*)(out + ((size_t)n*128 + o)*4) = v;
    }
}

extern "C" void kernel_launch(void* const* d_in, const int* in_sizes, int n_in,
                              void* d_out, int out_size, void* d_ws, size_t ws_size,
                              hipStream_t stream) {
    const float* node_feats = (const float*)d_in[0];
    const float* edge_attrs = (const float*)d_in[1];
    const float* edge_feats = (const float*)d_in[2];
    const float* lengths    = (const float*)d_in[3];
    const int*   edge_index = (const int*)d_in[4];
    const float* W_scalar   = (const float*)d_in[5];
    const float* W_up0      = (const float*)d_in[6];
    const float* W_up1      = (const float*)d_in[7];
    const float* W1         = (const float*)d_in[8];
    const float* b1         = (const float*)d_in[9];
    const float* W2         = (const float*)d_in[10];
    const float* b2         = (const float*)d_in[11];
    const float* W3         = (const float*)d_in[12];
    const float* Wout0      = (const float*)d_in[13];
    const float* Wout1      = (const float*)d_in[14];

    float* ws = (float*)d_ws;
    unsigned short* scalars_bf = (unsigned short*)ws;         // [0, 640k) slots
    float* h0    = ws + 640000;                               // N*128
    float* h1t   = ws + 1920000;                              // 3*N*128
    float* agg0  = ws + 5760000;                              // N*256
    float* agg1t = ws + 8320000;                              // 3*N*256 (ends 16,000,000)
    unsigned short* wpack = (unsigned short*)(ws + 16000000); // 118784 ushort = 59392 slots
    int* deg    = (int*)(ws + 16059392);                      // 10k
    int* cursor = (int*)(ws + 16069392);                      // 10k
    int* perm   = (int*)(ws + 16079392);                      // 160k (ends 16,239,392)
    if (ws_size < 16239392ull * 4ull) return;

    hipMemsetAsync(agg0, 0, 10240000ull * 4ull, stream);
    hipMemsetAsync(deg, 0, NN * 4, stream);
    convert_weights<<<464, 256, 0, stream>>>(W1, W2, W3, wpack);
    node_transform<<<1250, 256, 0, stream>>>(node_feats, W_scalar, W_up0, W_up1, scalars_bf, h0, h1t);
    hist_kernel<<<(NE + 255) / 256, 256, 0, stream>>>(edge_index, deg);
    scan_kernel<<<1, 256, 0, stream>>>(deg, cursor);
    perm_kernel<<<(NE + 255) / 256, 256, 0, stream>>>(edge_index, cursor, perm);
    edge_kernel<<<NE / TILE, 256, 0, stream>>>(scalars_bf, h0, h1t, edge_attrs, edge_feats, lengths,
                                               edge_index, perm, b1, b2, wpack, agg0, agg1t);
    output_transform<<<1250, 256, 0, stream>>>(agg0, agg1t, Wout0, Wout1, (float*)d_out);
}

// Round 6
// 240.052 us; speedup vs baseline: 8.5276x; 1.6963x over previous
//
#include <hip/hip_runtime.h>
#include <hip/hip_bf16.h>

#define NN 10000
#define NE 160000
#define TILE 32
#define A1S 296   // ushort stride for 288-col staging tile
#define A2S 136   // ushort stride for 128-col tiles

typedef __attribute__((ext_vector_type(8))) short short8;
typedef __attribute__((ext_vector_type(4))) float f32x4;

__device__ __forceinline__ float silu_f(float x) { return x / (1.0f + __expf(-x)); }
__device__ __forceinline__ unsigned short bf16u(float v) {
    __hip_bfloat16 b = __float2bfloat16(v);
    return *reinterpret_cast<unsigned short*>(&b);
}
__device__ __forceinline__ short8 pack8(float4 a, float4 b) {
    short8 r;
    r[0]=(short)bf16u(a.x); r[1]=(short)bf16u(a.y); r[2]=(short)bf16u(a.z); r[3]=(short)bf16u(a.w);
    r[4]=(short)bf16u(b.x); r[5]=(short)bf16u(b.y); r[6]=(short)bf16u(b.z); r[7]=(short)bf16u(b.w);
    return r;
}

// packed-weight ushort offsets
#define OFF_W1  0
#define OFF_W2  36864
#define OFF_W3  53248
#define OFF_WSC 118784
#define OFF_WU0 135168
#define OFF_WU1 151552
#define OFF_WO0 167936
#define OFF_WO1 200704
#define WP_TOTAL 233472

// ---------------- Kernel 0: pack all weights to bf16 fragment layout ----------------
// Wp[kt][n][kk] = W[kt*32+kk][n], zero-padded K where needed.
__global__ __launch_bounds__(256) void convert_weights(
    const float* __restrict__ W1, const float* __restrict__ W2,
    const float* __restrict__ W3, const float* __restrict__ Wsc,
    const float* __restrict__ Wu0, const float* __restrict__ Wu1,
    const float* __restrict__ Wo0, const float* __restrict__ Wo1,
    unsigned short* __restrict__ wp)
{
    int idx = blockIdx.x * 256 + threadIdx.x;
    if (idx >= WP_TOTAL) return;
    const float* src; int off, N, K;
    if      (idx < OFF_W2)  { src = W1;  off = OFF_W1;  N = 128; K = 265; }
    else if (idx < OFF_W3)  { src = W2;  off = OFF_W2;  N = 128; K = 128; }
    else if (idx < OFF_WSC) { src = W3;  off = OFF_W3;  N = 512; K = 128; }
    else if (idx < OFF_WU0) { src = Wsc; off = OFF_WSC; N = 128; K = 128; }
    else if (idx < OFF_WU1) { src = Wu0; off = OFF_WU0; N = 128; K = 128; }
    else if (idx < OFF_WO0) { src = Wu1; off = OFF_WU1; N = 128; K = 128; }
    else if (idx < OFF_WO1) { src = Wo0; off = OFF_WO0; N = 128; K = 256; }
    else                    { src = Wo1; off = OFF_WO1; N = 128; K = 256; }
    int j = idx - off;
    int kt = j / (N * 32);
    int rem = j % (N * 32);
    int n = rem >> 5, kk = rem & 31;
    int k = kt * 32 + kk;
    wp[idx] = (k < K) ? bf16u(src[k * N + n]) : (unsigned short)0;
}

// ---------------- Kernel 1: node transform (MFMA) ----------------
// 16 nodes/block, 4 waves; wave wv owns cols [wv*32, wv*32+32).
__global__ __launch_bounds__(256) void node_transform(
    const float* __restrict__ node_feats,
    const unsigned short* __restrict__ wp,
    unsigned short* __restrict__ scalars_bf,
    float* __restrict__ h0,
    float* __restrict__ h1t)
{
    __shared__ unsigned short xls[4 * 16 * 136];  // [x0, x1c0, x1c1, x1c2] each [16][136]
    const int t = threadIdx.x;
    const int bn = blockIdx.x * 16;

    for (int i = t; i < 16 * 512; i += 256) {
        int n = i >> 9, j = i & 511;
        unsigned short u = bf16u(node_feats[(size_t)(bn + n) * 512 + j]);
        if (j < 128) xls[n * 136 + j] = u;
        else {
            int jj = j - 128;
            int m = jj / 3;
            int c = jj - 3 * m;
            xls[(1 + c) * 2176 + n * 136 + m] = u;
        }
    }
    __syncthreads();

    const int wv = t >> 6, lane = t & 63, l16 = lane & 15, l4 = lane >> 4;
    const unsigned short* Wscp = wp + OFF_WSC;
    const unsigned short* Wu0p = wp + OFF_WU0;
    const unsigned short* Wu1p = wp + OFF_WU1;

    f32x4 asc[2] = {}, ah0[2] = {}, ah1[3][2] = {};
    for (int kt = 0; kt < 4; ++kt) {
        short8 ax0 = *(const short8*)(xls + l16 * 136 + kt * 32 + l4 * 8);
        short8 ax1[3];
        #pragma unroll
        for (int c = 0; c < 3; ++c)
            ax1[c] = *(const short8*)(xls + (1 + c) * 2176 + l16 * 136 + kt * 32 + l4 * 8);
        #pragma unroll
        for (int n = 0; n < 2; ++n) {
            int col = wv * 32 + n * 16 + l16;
            short8 bsc = *(const short8*)(Wscp + ((size_t)kt * 128 + col) * 32 + l4 * 8);
            short8 bu0 = *(const short8*)(Wu0p + ((size_t)kt * 128 + col) * 32 + l4 * 8);
            short8 bu1 = *(const short8*)(Wu1p + ((size_t)kt * 128 + col) * 32 + l4 * 8);
            asc[n] = __builtin_amdgcn_mfma_f32_16x16x32_bf16(ax0, bsc, asc[n], 0, 0, 0);
            ah0[n] = __builtin_amdgcn_mfma_f32_16x16x32_bf16(ax0, bu0, ah0[n], 0, 0, 0);
            #pragma unroll
            for (int c = 0; c < 3; ++c)
                ah1[c][n] = __builtin_amdgcn_mfma_f32_16x16x32_bf16(ax1[c], bu1, ah1[c][n], 0, 0, 0);
        }
    }
    const float inv = 0.08838834764831845f; // 1/sqrt(128)
    #pragma unroll
    for (int n = 0; n < 2; ++n) {
        int col = wv * 32 + n * 16 + l16;
        #pragma unroll
        for (int r = 0; r < 4; ++r) {
            int node = bn + l4 * 4 + r;
            scalars_bf[(size_t)node * 128 + col] = bf16u(asc[n][r] * inv);
            h0[(size_t)node * 128 + col] = ah0[n][r] * inv;
            #pragma unroll
            for (int c = 0; c < 3; ++c)
                h1t[(size_t)c * NN * 128 + (size_t)node * 128 + col] = ah1[c][n][r] * inv;
        }
    }
}

// ---------------- CSR build ----------------
__global__ __launch_bounds__(256) void hist_kernel(const int* __restrict__ edge_index,
                                                   int* __restrict__ deg) {
    int e = blockIdx.x * 256 + threadIdx.x;
    if (e < NE) atomicAdd(&deg[edge_index[NE + e]], 1);
}

__global__ __launch_bounds__(256) void scan_kernel(const int* __restrict__ deg,
                                                   int* __restrict__ cursor) {
    __shared__ int s[256];
    const int t = threadIdx.x;
    const int base = t * 40;
    int ld[40];
    int lsum = 0;
    #pragma unroll
    for (int i = 0; i < 40; ++i) {
        int idx = base + i;
        ld[i] = (idx < NN) ? deg[idx] : 0;
        lsum += ld[i];
    }
    s[t] = lsum;
    __syncthreads();
    for (int off = 1; off < 256; off <<= 1) {
        int u = (t >= off) ? s[t - off] : 0;
        __syncthreads();
        s[t] += u;
        __syncthreads();
    }
    int run = s[t] - lsum;
    #pragma unroll
    for (int i = 0; i < 40; ++i) {
        int idx = base + i;
        if (idx < NN) cursor[idx] = run;
        run += ld[i];
    }
}

__global__ __launch_bounds__(256) void perm_kernel(const int* __restrict__ edge_index,
                                                   int* __restrict__ cursor,
                                                   int* __restrict__ perm) {
    int e = blockIdx.x * 256 + threadIdx.x;
    if (e < NE) {
        int r = edge_index[NE + e];
        int pos = atomicAdd(&cursor[r], 1);
        perm[pos] = e;
    }
}

// ---------------- Kernel 2: MFMA edge MLP + TP + run-merged sorted scatter ----------------
__global__ __launch_bounds__(256, 5) void edge_kernel(
    const unsigned short* __restrict__ scalars_bf,
    const float* __restrict__ h0g,
    const float* __restrict__ h1t,
    const float* __restrict__ edge_attrs,
    const float* __restrict__ edge_feats,
    const float* __restrict__ lengths,
    const int* __restrict__ edge_index,
    const int* __restrict__ perm,
    const float* __restrict__ b1, const float* __restrict__ b2,
    const unsigned short* __restrict__ wp,
    float* __restrict__ agg0, float* __restrict__ agg1t)
{
    // LDS: A1 [0,18944) stride A1S; A2 [18944,27648) stride A2S;
    // A3 = A1 region stride A2S -> [0,8704); PKh fp32 [32][132] at [8704,25600) (dead A1-tail/A2).
    __shared__ unsigned char smem_u[27648];
    __shared__ int   eid_s[TILE];
    __shared__ int   s_s[TILE];
    __shared__ int   r_s[TILE];
    __shared__ float4 y_s[TILE];

    unsigned short* A1 = (unsigned short*)smem_u;
    unsigned short* A2 = (unsigned short*)(smem_u + 18944);
    unsigned short* A3 = A1;
    float* PKh = (float*)(smem_u + 8704);

    const int t = threadIdx.x;
    const int e0 = blockIdx.x * TILE;
    const int wv = t >> 6;
    const int lane = t & 63;
    const int l16 = lane & 15;
    const int l4 = lane >> 4;

    if (t < TILE) {
        int eid = perm[e0 + t];
        eid_s[t] = eid;
        s_s[t] = edge_index[eid];
        r_s[t] = edge_index[NE + eid];
        y_s[t] = *(const float4*)(edge_attrs + (size_t)eid * 4);
    }
    __syncthreads();

    // ---- stage mlp_in (bf16) into A1 ----
    {
        const int e = t >> 3, j = t & 7;
        const unsigned short* srow = scalars_bf + (size_t)s_s[e] * 128;
        const unsigned short* rrow = scalars_bf + (size_t)r_s[e] * 128;
        *(uint4*)(A1 + e*A1S + j*16)       = *(const uint4*)(srow + j*16);
        *(uint4*)(A1 + e*A1S + j*16 + 8)   = *(const uint4*)(srow + j*16 + 8);
        *(uint4*)(A1 + e*A1S + 128 + j*16)     = *(const uint4*)(rrow + j*16);
        *(uint4*)(A1 + e*A1S + 128 + j*16 + 8) = *(const uint4*)(rrow + j*16 + 8);
        A1[e*A1S + 256 + j] = bf16u(edge_feats[(size_t)eid_s[e] * 8 + j]);
        if (t < TILE) A1[t*A1S + 264] = bf16u(lengths[eid_s[t]]);
        for (int i = t; i < TILE * 23; i += 256) {
            int row = i / 23, c = 265 + (i - row * 23);
            A1[row*A1S + c] = 0;
        }
    }
    __syncthreads();

    const unsigned short* Wp1 = wp + OFF_W1;
    const unsigned short* Wp2 = wp + OFF_W2;
    const unsigned short* Wp3 = wp + OFF_W3;

    // ---- layer 1: (32 x 288) @ (288 x 128) ----
    {
        f32x4 acc[2][2] = {};
        for (int kt = 0; kt < 9; ++kt) {
            short8 a0 = *(const short8*)(A1 + (     l16)*A1S + kt*32 + l4*8);
            short8 a1 = *(const short8*)(A1 + (16 + l16)*A1S + kt*32 + l4*8);
            #pragma unroll
            for (int n = 0; n < 2; ++n) {
                int col = (2*wv + n)*16 + l16;
                short8 b = *(const short8*)(Wp1 + ((size_t)kt*128 + col)*32 + l4*8);
                acc[0][n] = __builtin_amdgcn_mfma_f32_16x16x32_bf16(a0, b, acc[0][n], 0, 0, 0);
                acc[1][n] = __builtin_amdgcn_mfma_f32_16x16x32_bf16(a1, b, acc[1][n], 0, 0, 0);
            }
        }
        #pragma unroll
        for (int n = 0; n < 2; ++n) {
            int col = (2*wv + n)*16 + l16;
            float bb = b1[col];
            #pragma unroll
            for (int m = 0; m < 2; ++m)
                #pragma unroll
                for (int r = 0; r < 4; ++r) {
                    int row = m*16 + l4*4 + r;
                    A2[row*A2S + col] = bf16u(silu_f(acc[m][n][r] + bb));
                }
        }
    }
    __syncthreads();

    // ---- layer 2: (32 x 128) @ (128 x 128) -> A3 ----
    {
        f32x4 acc[2][2] = {};
        for (int kt = 0; kt < 4; ++kt) {
            short8 a0 = *(const short8*)(A2 + (     l16)*A2S + kt*32 + l4*8);
            short8 a1 = *(const short8*)(A2 + (16 + l16)*A2S + kt*32 + l4*8);
            #pragma unroll
            for (int n = 0; n < 2; ++n) {
                int col = (2*wv + n)*16 + l16;
                short8 b = *(const short8*)(Wp2 + ((size_t)kt*128 + col)*32 + l4*8);
                acc[0][n] = __builtin_amdgcn_mfma_f32_16x16x32_bf16(a0, b, acc[0][n], 0, 0, 0);
                acc[1][n] = __builtin_amdgcn_mfma_f32_16x16x32_bf16(a1, b, acc[1][n], 0, 0, 0);
            }
        }
        #pragma unroll
        for (int n = 0; n < 2; ++n) {
            int col = (2*wv + n)*16 + l16;
            float bb = b2[col];
            #pragma unroll
            for (int m = 0; m < 2; ++m)
                #pragma unroll
                for (int r = 0; r < 4; ++r) {
                    int row = m*16 + l4*4 + r;
                    A3[row*A2S + col] = bf16u(silu_f(acc[m][n][r] + bb));
                }
        }
    }
    __syncthreads();   // A3 visible; A1 tail + A2 now dead -> PKh may use them

    // ---- layer 3: pass 0 = A/B, pass 1 = D/C; each pass in two 64-col halves ----
    const float rs3 = 0.57735026918962576f;
    #pragma unroll
    for (int pass = 0; pass < 2; ++pass) {
        const int base0 = pass ? 128 : 0;
        const int base1 = pass ? 384 : 256;
        for (int hh = 0; hh < 2; ++hh) {
            f32x4 acc[2][2] = {};   // [fam][m]
            for (int kt = 0; kt < 4; ++kt) {
                short8 a0 = *(const short8*)(A3 + (     l16)*A2S + kt*32 + l4*8);
                short8 a1 = *(const short8*)(A3 + (16 + l16)*A2S + kt*32 + l4*8);
                #pragma unroll
                for (int fam = 0; fam < 2; ++fam) {
                    int col = (fam ? base1 : base0) + hh*64 + wv*16 + l16;
                    short8 b = *(const short8*)(Wp3 + ((size_t)kt*512 + col)*32 + l4*8);
                    acc[fam][0] = __builtin_amdgcn_mfma_f32_16x16x32_bf16(a0, b, acc[fam][0], 0, 0, 0);
                    acc[fam][1] = __builtin_amdgcn_mfma_f32_16x16x32_bf16(a1, b, acc[fam][1], 0, 0, 0);
                }
            }
            #pragma unroll
            for (int fam = 0; fam < 2; ++fam)
                #pragma unroll
                for (int m = 0; m < 2; ++m)
                    #pragma unroll
                    for (int r = 0; r < 4; ++r) {
                        int row = m*16 + l4*4 + r;
                        float y0 = y_s[row].x;
                        float fold = (fam == 0) ? (pass ? rs3 : y0) : (pass ? y0 : 1.0f);
                        PKh[row*132 + fam*64 + wv*16 + l16] = acc[fam][m][r] * fold;
                    }
            __syncthreads();

            // scatter: thread t -> col o of this half, row quarter q (8 rows)
            {
                const int q = t >> 6, o = t & 63;
                const int ocol = hh*64 + o;
                const int rlo = q * 8;
                float ac0 = 0.f, ac1 = 0.f, ac2 = 0.f, ac3 = 0.f;
                int run_start = rlo;
                int prev_rn = r_s[rlo];

                auto flush = [&](int rn, bool interior) {
                    size_t b0 = (size_t)rn * 256 + base0 + ocol;
                    if (interior) {
                        agg0[b0] = ac0;
                        agg1t[0*(size_t)NN*256 + b0] = ac1;
                        agg1t[1*(size_t)NN*256 + b0] = ac2;
                        agg1t[2*(size_t)NN*256 + b0] = ac3;
                    } else {
                        atomicAdd(agg0 + b0, ac0);
                        atomicAdd(agg1t + 0*(size_t)NN*256 + b0, ac1);
                        atomicAdd(agg1t + 1*(size_t)NN*256 + b0, ac2);
                        atomicAdd(agg1t + 2*(size_t)NN*256 + b0, ac3);
                    }
                };

                for (int row = rlo; row < rlo + 8; ++row) {
                    int rn = r_s[row];
                    if (rn != prev_rn) {
                        flush(prev_rn, run_start > rlo);
                        ac0 = ac1 = ac2 = ac3 = 0.f;
                        run_start = row;
                        prev_rn = rn;
                    }
                    int sn = s_s[row];
                    float w0 = PKh[row*132 + o];
                    float w1 = PKh[row*132 + 64 + o];
                    float4 y = y_s[row];
                    if (pass == 0) {
                        float x = h0g[(size_t)sn*128 + ocol];
                        ac0 = fmaf(x, w0, ac0);            // A (y0 folded)
                        float xb = x * w1;                 // B
                        ac1 = fmaf(xb, y.y, ac1);
                        ac2 = fmaf(xb, y.z, ac2);
                        ac3 = fmaf(xb, y.w, ac3);
                    } else {
                        float xx = h1t[0*NN*128 + (size_t)sn*128 + ocol];
                        float xy = h1t[1*NN*128 + (size_t)sn*128 + ocol];
                        float xz = h1t[2*NN*128 + (size_t)sn*128 + ocol];
                        float dd = xx*y.y + xy*y.z + xz*y.w;  // D (rs3 folded into w0)
                        ac0 = fmaf(dd, w0, ac0);
                        ac1 = fmaf(xx, w1, ac1);           // C (y0 folded into w1)
                        ac2 = fmaf(xy, w1, ac2);
                        ac3 = fmaf(xz, w1, ac3);
                    }
                }
                flush(prev_rn, false);
            }
            __syncthreads();
        }
    }
}

// ---------------- Kernel 3: output transform (MFMA) ----------------
// 16 nodes/block; A = [agg0, agg1t(c=0,1,2)] bf16-staged in LDS; B = Wout0/Wout1 packed.
__global__ __launch_bounds__(256) void output_transform(
    const float* __restrict__ agg0,
    const float* __restrict__ agg1t,
    const unsigned short* __restrict__ wp,
    float* __restrict__ out)
{
    __shared__ unsigned short As[4][16 * 264];
    const int t = threadIdx.x;
    const int bn = blockIdx.x * 16;

    for (int i = t; i < 2048; i += 256) {        // 8-elem chunks: 4 mats * 16 nodes * 32
        int mat = i >> 9;
        int rem = i & 511;
        int n = rem >> 5;
        int ko = (rem & 31) * 8;
        const float* src = (mat == 0)
            ? (agg0 + (size_t)(bn + n) * 256 + ko)
            : (agg1t + (size_t)(mat - 1) * NN * 256 + (size_t)(bn + n) * 256 + ko);
        float4 v0 = *(const float4*)(src);
        float4 v1 = *(const float4*)(src + 4);
        *(short8*)(&As[mat][n * 264 + ko]) = pack8(v0, v1);
    }
    __syncthreads();

    const int wv = t >> 6, lane = t & 63, l16 = lane & 15, l4 = lane >> 4;
    const unsigned short* Wo0p = wp + OFF_WO0;
    const unsigned short* Wo1p = wp + OFF_WO1;

    f32x4 acc[2][4] = {};
    for (int kt = 0; kt < 8; ++kt) {
        short8 a0 = *(const short8*)(&As[0][l16 * 264 + kt * 32 + l4 * 8]);
        short8 a1 = *(const short8*)(&As[1][l16 * 264 + kt * 32 + l4 * 8]);
        short8 a2 = *(const short8*)(&As[2][l16 * 264 + kt * 32 + l4 * 8]);
        short8 a3 = *(const short8*)(&As[3][l16 * 264 + kt * 32 + l4 * 8]);
        #pragma unroll
        for (int n = 0; n < 2; ++n) {
            int col = wv * 32 + n * 16 + l16;
            short8 bw0 = *(const short8*)(Wo0p + ((size_t)kt * 128 + col) * 32 + l4 * 8);
            short8 bw1 = *(const short8*)(Wo1p + ((size_t)kt * 128 + col) * 32 + l4 * 8);
            acc[n][0] = __builtin_amdgcn_mfma_f32_16x16x32_bf16(a0, bw0, acc[n][0], 0, 0, 0);
            acc[n][1] = __builtin_amdgcn_mfma_f32_16x16x32_bf16(a1, bw1, acc[n][1], 0, 0, 0);
            acc[n][2] = __builtin_amdgcn_mfma_f32_16x16x32_bf16(a2, bw1, acc[n][2], 0, 0, 0);
            acc[n][3] = __builtin_amdgcn_mfma_f32_16x16x32_bf16(a3, bw1, acc[n][3], 0, 0, 0);
        }
    }
    const float scale = 0.00390625f; // 1/(sqrt(256)*16)
    #pragma unroll
    for (int n = 0; n < 2; ++n) {
        int col = wv * 32 + n * 16 + l16;
        #pragma unroll
        for (int r = 0; r < 4; ++r) {
            int node = bn + l4 * 4 + r;
            float4 v = make_float4(acc[n][0][r] * scale, acc[n][1][r] * scale,
                                   acc[n][2][r] * scale, acc[n][3][r] * scale);
            *(float4*)(out + ((size_t)node * 128 + col) * 4) = v;
        }
    }
}

extern "C" void kernel_launch(void* const* d_in, const int* in_sizes, int n_in,
                              void* d_out, int out_size, void* d_ws, size_t ws_size,
                              hipStream_t stream) {
    const float* node_feats = (const float*)d_in[0];
    const float* edge_attrs = (const float*)d_in[1];
    const float* edge_feats = (const float*)d_in[2];
    const float* lengths    = (const float*)d_in[3];
    const int*   edge_index = (const int*)d_in[4];
    const float* W_scalar   = (const float*)d_in[5];
    const float* W_up0      = (const float*)d_in[6];
    const float* W_up1      = (const float*)d_in[7];
    const float* W1         = (const float*)d_in[8];
    const float* b1         = (const float*)d_in[9];
    const float* W2         = (const float*)d_in[10];
    const float* b2         = (const float*)d_in[11];
    const float* W3         = (const float*)d_in[12];
    const float* Wout0      = (const float*)d_in[13];
    const float* Wout1      = (const float*)d_in[14];

    float* ws = (float*)d_ws;
    unsigned short* scalars_bf = (unsigned short*)ws;         // [0, 640k) slots
    float* h0    = ws + 640000;                               // N*128
    float* h1t   = ws + 1920000;                              // 3*N*128
    float* agg0  = ws + 5760000;                              // N*256
    float* agg1t = ws + 8320000;                              // 3*N*256 (ends 16,000,000)
    unsigned short* wpack = (unsigned short*)(ws + 16000000); // 233472 ushort = 116736 slots
    int* deg    = (int*)(ws + 16116736);                      // 10k
    int* cursor = (int*)(ws + 16126736);                      // 10k
    int* perm   = (int*)(ws + 16136736);                      // 160k (ends 16,296,736)
    if (ws_size < 16296736ull * 4ull) return;

    hipMemsetAsync(agg0, 0, 10240000ull * 4ull, stream);
    hipMemsetAsync(deg, 0, NN * 4, stream);
    convert_weights<<<(WP_TOTAL + 255) / 256, 256, 0, stream>>>(
        W1, W2, W3, W_scalar, W_up0, W_up1, Wout0, Wout1, wpack);
    node_transform<<<625, 256, 0, stream>>>(node_feats, wpack, scalars_bf, h0, h1t);
    hist_kernel<<<(NE + 255) / 256, 256, 0, stream>>>(edge_index, deg);
    scan_kernel<<<1, 256, 0, stream>>>(deg, cursor);
    perm_kernel<<<(NE + 255) / 256, 256, 0, stream>>>(edge_index, cursor, perm);
    edge_kernel<<<NE / TILE, 256, 0, stream>>>(scalars_bf, h0, h1t, edge_attrs, edge_feats, lengths,
                                               edge_index, perm, b1, b2, wpack, agg0, agg1t);
    output_transform<<<625, 256, 0, stream>>>(agg0, agg1t, wpack, (float*)d_out);
}